// Round 7
// baseline (533.747 us; speedup 1.0000x reference)
//
#include <hip/hip_runtime.h>
#include <hip/hip_bf16.h>

// Decoder loss: keep-mask (kth-value threshold + local max), BCE coord loss,
// bidirectional NN recolor + L1 rgb loss.
// L=16384 candidates, N=10000 targets, K=8 (collapses to argmin; R1-proven).
// R7: 3 kernels. Kernel boundaries cost ~9us each (R6 analysis); grid.sync
//     costs ~40us (R4) — so fusion uses only deadlock-free device patterns:
//     "last block does the tail" completion counters + one bounded spin.

#define SCAN_T 256
typedef unsigned long long ull;

// ---- Kernel 1: init + monotone keys + per-8 local max ----------------------
__global__ __launch_bounds__(256) void k_prep(
    const float* __restrict__ pred, const float* __restrict__ txyz,
    float4* __restrict__ ttile, float4* __restrict__ numden,
    int* __restrict__ zerohit, ull* __restrict__ tmin, ull* __restrict__ fmin,
    unsigned int* __restrict__ key, unsigned char* __restrict__ islm,
    unsigned int* __restrict__ donex, unsigned int* __restrict__ gdone,
    int* __restrict__ counters, float* __restrict__ out, int L, int N) {
  int gidx = blockIdx.x * 256 + threadIdx.x;
  int gsz = (int)gridDim.x * 256;
  for (int i = gidx; i < N; i += gsz) {
    float x = txyz[3*i], y = txyz[3*i+1], z = txyz[3*i+2];
    ttile[i] = make_float4(x, y, z, fmaf(x, x, fmaf(y, y, z * z)));
    tmin[i] = ~0ull;
  }
  for (int i = gidx; i < L; i += gsz) {
    numden[i] = make_float4(0.f, 0.f, 0.f, 0.f);
    zerohit[i] = 0;
    fmin[i] = ~0ull;
  }
  if (gidx < 64) donex[gidx] = 0u;
  if (gidx == 64) gdone[0] = 0u;
  if (gidx < 8) counters[gidx] = 0;
  if (gidx < 2) out[gidx] = 0.f;
  int ngroups = L >> 3;
  for (int g = gidx; g < ngroups; g += gsz) {
    const float4* pv = (const float4*)pred + (size_t)g * 2;
    float4 a = pv[0], b = pv[1];
    float v[8] = {a.x, a.y, a.z, a.w, b.x, b.y, b.z, b.w};
    int bi = 0; float bv = v[0];
    #pragma unroll
    for (int j = 1; j < 8; ++j) if (v[j] > bv) { bv = v[j]; bi = j; }
    unsigned int kk[8];
    ull lmpack = 0ull;
    #pragma unroll
    for (int j = 0; j < 8; ++j) {
      unsigned int fb = __float_as_uint(v[j]);
      unsigned int mk = (fb & 0x80000000u) ? ~fb : (fb | 0x80000000u);
      if (j == bi) { mk = 0xFF800000u; lmpack |= 1ull << (8 * j); }  // +inf
      kk[j] = mk;
    }
    ((uint4*)key)[g*2]   = make_uint4(kk[0], kk[1], kk[2], kk[3]);
    ((uint4*)key)[g*2+1] = make_uint4(kk[4], kk[5], kk[6], kk[7]);
    *(ull*)(islm + (size_t)g * 8) = lmpack;
  }
}

// ---- helper: pick bin containing rank from LDS hist (wave 0) ---------------
__device__ __forceinline__ void select_bin(
    unsigned int* hist, int nb, unsigned int rank,
    unsigned int* sB, unsigned int* sR, int tid) {
  if (tid < 64) {
    int g = nb >> 6;
    unsigned int sum = 0;
    for (int j = 0; j < g; ++j) sum += hist[tid * g + j];
    unsigned int incl = sum;
    for (int o = 1; o < 64; o <<= 1) {
      unsigned int v = __shfl_up(incl, o);
      if (tid >= o) incl += v;
    }
    unsigned int excl = incl - sum;
    bool cond = (rank >= excl) && (rank < incl);
    unsigned long long bal = __ballot(cond);
    int first = __ffsll((long long)bal) - 1;
    if (tid == first) {
      unsigned int r = rank - excl, cum = 0;
      for (int j = 0; j < g; ++j) {
        unsigned int c = hist[tid * g + j];
        if (r < cum + c) { *sB = (unsigned int)(tid * g + j); *sR = r - cum; break; }
        cum += c;
      }
    }
  }
}

// ---- Kernel 2: last block selects threshold; all blocks keep/compact/BCE ---
// One-way bounded spin: producers never wait, so deadlock-free. Flag's 0xAA
// poison != sentinel 1, so no pre-zeroing needed.
__global__ __launch_bounds__(256) void k_selkeep(
    const float* __restrict__ pred, const unsigned int* __restrict__ key,
    const unsigned char* __restrict__ islm, const int* __restrict__ pnum_p,
    const float* __restrict__ cxyz, const int* __restrict__ ktgt,
    int* __restrict__ keep, float4* __restrict__ klist, int* __restrict__ kidx,
    int* __restrict__ counters, unsigned int* __restrict__ thrbits,
    unsigned int* __restrict__ flag, float* __restrict__ out, int L) {
  __shared__ unsigned int hist[2048];
  __shared__ unsigned int sB, sR;
  int tid = threadIdx.x;
  if (blockIdx.x == gridDim.x - 1) {
    // ---- exact rank select (R6-proven 3-sweep radix) ----
    unsigned int rank = (unsigned int)(L - pnum_p[0] - 1);
    const uint4* k4 = (const uint4*)key;
    int n4 = L >> 2;
    for (int b = tid; b < 2048; b += 256) hist[b] = 0u;
    __syncthreads();
    for (int i = tid; i < n4; i += 256) {
      uint4 v = k4[i];
      atomicAdd(&hist[v.x >> 21], 1u); atomicAdd(&hist[v.y >> 21], 1u);
      atomicAdd(&hist[v.z >> 21], 1u); atomicAdd(&hist[v.w >> 21], 1u);
    }
    __syncthreads();
    select_bin(hist, 2048, rank, &sB, &sR, tid);
    __syncthreads();
    unsigned int B1 = sB, R1 = sR;
    for (int b = tid; b < 2048; b += 256) hist[b] = 0u;
    __syncthreads();
    for (int i = tid; i < n4; i += 256) {
      uint4 v = k4[i];
      if ((v.x >> 21) == B1) atomicAdd(&hist[(v.x >> 10) & 2047u], 1u);
      if ((v.y >> 21) == B1) atomicAdd(&hist[(v.y >> 10) & 2047u], 1u);
      if ((v.z >> 21) == B1) atomicAdd(&hist[(v.z >> 10) & 2047u], 1u);
      if ((v.w >> 21) == B1) atomicAdd(&hist[(v.w >> 10) & 2047u], 1u);
    }
    __syncthreads();
    select_bin(hist, 2048, R1, &sB, &sR, tid);
    __syncthreads();
    unsigned int B2 = sB, R2 = sR;
    for (int b = tid; b < 1024; b += 256) hist[b] = 0u;
    __syncthreads();
    unsigned int top22 = (B1 << 11) | B2;
    for (int i = tid; i < n4; i += 256) {
      uint4 v = k4[i];
      if ((v.x >> 10) == top22) atomicAdd(&hist[v.x & 1023u], 1u);
      if ((v.y >> 10) == top22) atomicAdd(&hist[v.y & 1023u], 1u);
      if ((v.z >> 10) == top22) atomicAdd(&hist[v.z & 1023u], 1u);
      if ((v.w >> 10) == top22) atomicAdd(&hist[v.w & 1023u], 1u);
    }
    __syncthreads();
    select_bin(hist, 1024, R2, &sB, &sR, tid);
    __syncthreads();
    if (tid == 0) {
      unsigned int fkey = (B1 << 21) | (B2 << 10) | sB;
      unsigned int fb = (fkey & 0x80000000u) ? (fkey & 0x7FFFFFFFu) : ~fkey;
      atomicExch(thrbits, fb);       // publish via atomics (coherent point)
      __threadfence();
      atomicExch(flag, 1u);          // release
    }
  }
  // ---- all blocks: wait for thr (bounded, one-way) ----
  if (tid == 0) {
    while (atomicAdd(flag, 0u) != 1u) __builtin_amdgcn_s_sleep(2);
  }
  __syncthreads();
  float thr = __uint_as_float(atomicAdd(thrbits, 0u));
  // ---- keep mask + compaction + BCE ----
  int i = blockIdx.x * 256 + tid;
  float term = 0.f;
  if (i < L) {
    float p = pred[i];
    bool kp = (p > thr) || islm[i];
    keep[i] = kp ? 1 : 0;
    if (kp) {
      int pos = atomicAdd(&counters[0], 1);   // order irrelevant (no ties)
      float x = cxyz[3*i], y = cxyz[3*i+1], z = cxyz[3*i+2];
      klist[pos] = make_float4(x, y, z, fmaf(x, x, fmaf(y, y, z * z)));
      kidx[pos] = i;
    }
    float t = (float)ktgt[i];
    term = fmaxf(p, 0.f) - p * t + log1pf(expf(-fabsf(p)));
  }
  for (int o = 32; o > 0; o >>= 1) term += __shfl_down(term, o);
  if ((tid & 63) == 0) atomicAdd(&out[0], term);
}

// ---- Kernel 3: bwd scan + fwd scan + scatter tail + loss tail --------------
// Completion-counter pattern only ("last arriving block does the tail") —
// no block ever waits; deadlock-free by construction.
__global__ __launch_bounds__(SCAN_T) void k_scan(
    const float* __restrict__ txyz, const float* __restrict__ crgb,
    const float* __restrict__ trgb, const float4* __restrict__ klist,
    const int* __restrict__ kidx, const float4* __restrict__ ttile,
    const int* __restrict__ counters, const int* __restrict__ keep,
    ull* __restrict__ tmin, ull* __restrict__ fmin,
    float4* __restrict__ numden, int* __restrict__ zerohit,
    float4* __restrict__ zcolor, unsigned int* __restrict__ donex,
    unsigned int* __restrict__ gdone, float* __restrict__ out,
    int L, int N, int YB, int total) {
  __shared__ float4 tile[SCAN_T];
  __shared__ unsigned int sCnt;
  int tid = threadIdx.x, x = blockIdx.x, y = blockIdx.y;
  int kc = counters[0];

  if (y < YB) {
    // ---------- backward role: targets x*256.. vs kept-candidate chunk y ----
    int c0 = y * 512, c1 = min(c0 + 512, kc);
    if (x * 256 < N && c0 < kc) {
      int t = x * 256 + tid;
      bool act = t < N;
      float tx = 0.f, ty = 0.f, tz = 0.f;
      if (act) { tx = txyz[3*t]; ty = txyz[3*t+1]; tz = txyz[3*t+2]; }
      float ntx = -2.f * tx, nty = -2.f * ty, ntz = -2.f * tz;
      float best = 3e38f; int bpos = -1;
      for (int tb = c0; tb < c1; tb += SCAN_T) {
        int cnt = min(SCAN_T, c1 - tb);
        if (tid < cnt) tile[tid] = klist[tb + tid];
        __syncthreads();
        #pragma unroll 8
        for (int c = 0; c < cnt; ++c) {
          float4 cd = tile[c];
          // monotone surrogate |c|^2 - 2 t.c (argmin-equiv to |t-c|^2)
          float d = fmaf(ntx, cd.x, cd.w);
          d = fmaf(nty, cd.y, d);
          d = fmaf(ntz, cd.z, d);
          if (d < best) { best = d; bpos = tb + c; }
        }
        __syncthreads();
      }
      if (act && bpos >= 0) {
        float4 cd = klist[bpos];
        float dx = tx - cd.x, dy = ty - cd.y, dz = tz - cd.z;
        float dtrue = fmaf(dx, dx, fmaf(dy, dy, dz * dz));  // exact (R1-proven)
        ull pack = ((ull)__float_as_uint(dtrue) << 32) | (unsigned int)kidx[bpos];
        atomicMin(&tmin[t], pack);
      }
    }
    // per-x completion; last arriving block scatters this target group
    __threadfence();
    __syncthreads();
    if (tid == 0) sCnt = atomicAdd(&donex[x], 1u);
    __syncthreads();
    if (sCnt == (unsigned)(YB - 1)) {
      __threadfence();  // acquire
      int t = x * 256 + tid;
      if (t < N) {
        ull pack = atomicAdd(&tmin[t], 0ull);   // coherent read
        float d = __uint_as_float((unsigned int)(pack >> 32));
        int idx = (int)(pack & 0xFFFFFFFFull);
        float r = trgb[3*t], g = trgb[3*t+1], b = trgb[3*t+2];
        if (d == 0.0f) {
          zerohit[idx] = 1;
          zcolor[idx] = make_float4(r, g, b, 0.f);
        } else {
          float w = 1.0f / sqrtf(fmaxf(d, 1e-30f));
          atomicAdd(&numden[idx].x, r * w);
          atomicAdd(&numden[idx].y, g * w);
          atomicAdd(&numden[idx].z, b * w);
          atomicAdd(&numden[idx].w, w);
        }
      }
    }
  } else {
    // ---------- forward role: ALL kept candidates vs target chunk ----------
    int ty = y - YB;
    int t0 = ty * 512, t1 = min(t0 + 512, N);
    if (x * 256 < kc) {
      int e = x * 256 + tid;
      bool act = e < kc;
      float cx = 0.f, cy = 0.f, cz = 0.f, c2 = 0.f;
      int l = 0;
      if (act) {
        float4 cd = klist[e];
        cx = cd.x; cy = cd.y; cz = cd.z; c2 = cd.w;
        l = kidx[e];
      }
      float ncx = -2.f * cx, ncy = -2.f * cy, ncz = -2.f * cz;
      float best = 3e38f; int bidx = 0;
      for (int tb = t0; tb < t1; tb += SCAN_T) {
        int cnt = min(SCAN_T, t1 - tb);
        if (tid < cnt) tile[tid] = ttile[tb + tid];
        __syncthreads();
        #pragma unroll 8
        for (int c = 0; c < cnt; ++c) {
          float4 td = tile[c];
          float d = fmaf(ncx, td.x, td.w);
          d = fmaf(ncy, td.y, d);
          d = fmaf(ncz, td.z, d);
          if (d < best) { best = d; bidx = tb + c; }
        }
        __syncthreads();
      }
      if (act) {
        float dkey = fmaxf(best + c2, 0.f);   // consistent merge key
        ull pack = ((ull)__float_as_uint(dkey) << 32) | (unsigned int)bidx;
        atomicMin(&fmin[l], pack);
      }
    }
  }

  // ---------- global completion; last arriving block computes the loss ------
  __threadfence();
  __syncthreads();
  if (tid == 0) sCnt = atomicAdd(gdone, 1u);
  __syncthreads();
  if (sCnt == (unsigned)(total - 1)) {
    __threadfence();  // acquire: all scatters/fwd mins released before here
    float loss = 0.f;
    for (int l = tid; l < L; l += SCAN_T) {
      if (keep[l]) {
        float rr, rg, rb;
        if (zerohit[l]) {
          float4 z = zcolor[l]; rr = z.x; rg = z.y; rb = z.z;
        } else {
          float4 nd = numden[l];
          if (nd.w != 0.f) { rr = nd.x / nd.w; rg = nd.y / nd.w; rb = nd.z / nd.w; }
          else {
            int ti = (int)(fmin[l] & 0xFFFFFFFFull);
            rr = trgb[3*ti]; rg = trgb[3*ti+1]; rb = trgb[3*ti+2];
          }
        }
        float sr = crgb[3*l]*255.f, sg = crgb[3*l+1]*255.f, sb = crgb[3*l+2]*255.f;
        loss += fabsf(sr - rr) + fabsf(sg - rg) + fabsf(sb - rb);
      }
    }
    for (int o = 32; o > 0; o >>= 1) loss += __shfl_down(loss, o);
    if ((tid & 63) == 0) atomicAdd(&out[1], loss);
  }
}

extern "C" void kernel_launch(void* const* d_in, const int* in_sizes, int n_in,
                              void* d_out, int out_size, void* d_ws, size_t ws_size,
                              hipStream_t stream) {
  const float* pred = (const float*)d_in[0];
  const float* cxyz = (const float*)d_in[1];
  const float* crgb = (const float*)d_in[2];
  const float* txyz = (const float*)d_in[3];
  const float* trgb = (const float*)d_in[4];
  const int*   ktgt = (const int*)d_in[5];
  const int*   pnum = (const int*)d_in[6];
  int L = in_sizes[0];
  int N = in_sizes[3] / 3;

  // workspace layout: 16B arrays first, then 8B, 4B, bytes
  char* ws = (char*)d_ws;
  size_t off = 0;
  float4* klist  = (float4*)(ws + off);   off += (size_t)L * 16;
  float4* ttile  = (float4*)(ws + off);   off += (size_t)((N + 3) & ~3) * 16;
  float4* numden = (float4*)(ws + off);   off += (size_t)L * 16;
  float4* zcolor = (float4*)(ws + off);   off += (size_t)L * 16;
  unsigned int* key = (unsigned int*)(ws + off); off += (size_t)L * 4;  // uint4-aligned
  ull* tmin      = (ull*)(ws + off);      off += (size_t)((N + 1) & ~1) * 8;
  ull* fmin      = (ull*)(ws + off);      off += (size_t)L * 8;
  int* keep      = (int*)(ws + off);      off += (size_t)L * 4;
  int* kidx      = (int*)(ws + off);      off += (size_t)L * 4;
  int* zerohit   = (int*)(ws + off);      off += (size_t)L * 4;
  unsigned int* donex = (unsigned int*)(ws + off); off += 64 * 4;
  unsigned int* gdone = (unsigned int*)(ws + off); off += 16;
  unsigned int* thrbits = (unsigned int*)(ws + off); off += 16;
  unsigned int* flag = (unsigned int*)(ws + off);  off += 16;
  int* counters  = (int*)(ws + off);      off += 256;   // [0]=kcount
  unsigned char* islm = (unsigned char*)(ws + off); off += ((size_t)L + 15) & ~15ull;
  float* out = (float*)d_out;

  int nbL = (L + 255) / 256;            // 64
  int YB = (L + 511) / 512;             // 32 (max kept chunks)
  int YF = (N + 511) / 512;             // 20 (target chunks)
  int total = nbL * (YB + YF);

  k_prep<<<nbL, 256, 0, stream>>>(
      pred, txyz, ttile, numden, zerohit, tmin, fmin, key, islm,
      donex, gdone, counters, out, L, N);

  k_selkeep<<<nbL, 256, 0, stream>>>(
      pred, key, islm, pnum, cxyz, ktgt, keep, klist, kidx,
      counters, thrbits, flag, out, L);

  dim3 g3(nbL, YB + YF);
  k_scan<<<g3, SCAN_T, 0, stream>>>(
      txyz, crgb, trgb, klist, kidx, ttile, counters, keep,
      tmin, fmin, numden, zerohit, zcolor, donex, gdone, out,
      L, N, YB, total);
}

// Round 8
// 140.304 us; speedup vs baseline: 3.8042x; 3.8042x over previous
//
#include <hip/hip_runtime.h>
#include <hip/hip_bf16.h>

// Decoder loss: keep-mask (kth-value threshold + local max), BCE coord loss,
// bidirectional NN recolor + L1 rgb loss.
// L=16384 candidates, N=10000 targets, K=8 (collapses to argmin; R1-proven).
// R8: R6 structure minus 2 launches. Hard-learned rules for this part:
//   - grid.sync ~40us each (R4), mass __threadfence ~0.1ms+ (R7): NEVER fuse
//     across device-scope ordering. Kernel boundary (~10us) is the cheap sync.
//   - LDS-tiled broadcast scans, not uniform global streams (R5: 7x slower).
//   - bwd & fwd scans are independent -> one dual-role grid, zero sync needed.
//   - fwd scans ALL kept (R7-proven exact); kills k_empty + elist.

#define SCAN_T 256
typedef unsigned long long ull;

// ---- Kernel 1: init + monotone keys + per-8 local max ----------------------
__global__ __launch_bounds__(256) void k_prep(
    const float* __restrict__ pred, const float* __restrict__ txyz,
    float4* __restrict__ ttile, float4* __restrict__ numden,
    int* __restrict__ zerohit, ull* __restrict__ tmin, ull* __restrict__ fmin,
    unsigned int* __restrict__ key, unsigned char* __restrict__ islm,
    int* __restrict__ counters, float* __restrict__ out, int L, int N) {
  int gidx = blockIdx.x * 256 + threadIdx.x;
  int gsz = (int)gridDim.x * 256;
  for (int i = gidx; i < N; i += gsz) {
    float x = txyz[3*i], y = txyz[3*i+1], z = txyz[3*i+2];
    ttile[i] = make_float4(x, y, z, fmaf(x, x, fmaf(y, y, z * z)));
    tmin[i] = ~0ull;
  }
  for (int i = gidx; i < L; i += gsz) {
    numden[i] = make_float4(0.f, 0.f, 0.f, 0.f);
    zerohit[i] = 0;
    fmin[i] = ~0ull;
  }
  if (gidx < 8) counters[gidx] = 0;
  if (gidx < 2) out[gidx] = 0.f;
  int ngroups = L >> 3;
  for (int g = gidx; g < ngroups; g += gsz) {
    const float4* pv = (const float4*)pred + (size_t)g * 2;
    float4 a = pv[0], b = pv[1];
    float v[8] = {a.x, a.y, a.z, a.w, b.x, b.y, b.z, b.w};
    int bi = 0; float bv = v[0];
    #pragma unroll
    for (int j = 1; j < 8; ++j) if (v[j] > bv) { bv = v[j]; bi = j; }
    unsigned int kk[8];
    ull lmpack = 0ull;
    #pragma unroll
    for (int j = 0; j < 8; ++j) {
      unsigned int fb = __float_as_uint(v[j]);
      unsigned int mk = (fb & 0x80000000u) ? ~fb : (fb | 0x80000000u);
      if (j == bi) { mk = 0xFF800000u; lmpack |= 1ull << (8 * j); }  // +inf
      kk[j] = mk;
    }
    ((uint4*)key)[g*2]   = make_uint4(kk[0], kk[1], kk[2], kk[3]);
    ((uint4*)key)[g*2+1] = make_uint4(kk[4], kk[5], kk[6], kk[7]);
    *(ull*)(islm + (size_t)g * 8) = lmpack;
  }
}

// ---- helper: pick bin containing rank from LDS hist (wave 0) ---------------
__device__ __forceinline__ void select_bin(
    unsigned int* hist, int nb, unsigned int rank,
    unsigned int* sB, unsigned int* sR, int tid) {
  if (tid < 64) {
    int g = nb >> 6;
    unsigned int sum = 0;
    for (int j = 0; j < g; ++j) sum += hist[tid * g + j];
    unsigned int incl = sum;
    for (int o = 1; o < 64; o <<= 1) {
      unsigned int v = __shfl_up(incl, o);
      if (tid >= o) incl += v;
    }
    unsigned int excl = incl - sum;
    bool cond = (rank >= excl) && (rank < incl);
    unsigned long long bal = __ballot(cond);
    int first = __ffsll((long long)bal) - 1;
    if (tid == first) {
      unsigned int r = rank - excl, cum = 0;
      for (int j = 0; j < g; ++j) {
        unsigned int c = hist[tid * g + j];
        if (r < cum + c) { *sB = (unsigned int)(tid * g + j); *sR = r - cum; break; }
        cum += c;
      }
    }
  }
}

// ---- Kernel 2: exact rank select, self-contained (1 block, 3 sweeps) -------
__global__ __launch_bounds__(256) void k_sel(
    const unsigned int* __restrict__ key, const int* __restrict__ pnum_p,
    float* __restrict__ thr_out, int L) {
  __shared__ unsigned int hist[2048];
  __shared__ unsigned int sB, sR;
  int tid = threadIdx.x;
  unsigned int rank = (unsigned int)(L - pnum_p[0] - 1);
  const uint4* k4 = (const uint4*)key;
  int n4 = L >> 2;
  for (int b = tid; b < 2048; b += 256) hist[b] = 0u;
  __syncthreads();
  for (int i = tid; i < n4; i += 256) {
    uint4 v = k4[i];
    atomicAdd(&hist[v.x >> 21], 1u); atomicAdd(&hist[v.y >> 21], 1u);
    atomicAdd(&hist[v.z >> 21], 1u); atomicAdd(&hist[v.w >> 21], 1u);
  }
  __syncthreads();
  select_bin(hist, 2048, rank, &sB, &sR, tid);
  __syncthreads();
  unsigned int B1 = sB, R1 = sR;
  for (int b = tid; b < 2048; b += 256) hist[b] = 0u;
  __syncthreads();
  for (int i = tid; i < n4; i += 256) {
    uint4 v = k4[i];
    if ((v.x >> 21) == B1) atomicAdd(&hist[(v.x >> 10) & 2047u], 1u);
    if ((v.y >> 21) == B1) atomicAdd(&hist[(v.y >> 10) & 2047u], 1u);
    if ((v.z >> 21) == B1) atomicAdd(&hist[(v.z >> 10) & 2047u], 1u);
    if ((v.w >> 21) == B1) atomicAdd(&hist[(v.w >> 10) & 2047u], 1u);
  }
  __syncthreads();
  select_bin(hist, 2048, R1, &sB, &sR, tid);
  __syncthreads();
  unsigned int B2 = sB, R2 = sR;
  for (int b = tid; b < 1024; b += 256) hist[b] = 0u;
  __syncthreads();
  unsigned int top22 = (B1 << 11) | B2;
  for (int i = tid; i < n4; i += 256) {
    uint4 v = k4[i];
    if ((v.x >> 10) == top22) atomicAdd(&hist[v.x & 1023u], 1u);
    if ((v.y >> 10) == top22) atomicAdd(&hist[v.y & 1023u], 1u);
    if ((v.z >> 10) == top22) atomicAdd(&hist[v.z & 1023u], 1u);
    if ((v.w >> 10) == top22) atomicAdd(&hist[v.w & 1023u], 1u);
  }
  __syncthreads();
  select_bin(hist, 1024, R2, &sB, &sR, tid);
  __syncthreads();
  if (tid == 0) {
    unsigned int fkey = (B1 << 21) | (B2 << 10) | sB;
    unsigned int fb = (fkey & 0x80000000u) ? (fkey & 0x7FFFFFFFu) : ~fkey;
    thr_out[0] = __uint_as_float(fb);
  }
}

// ---- Kernel 3: keep mask + compaction + BCE reduce -------------------------
__global__ __launch_bounds__(256) void k_keepc(
    const float* __restrict__ pred, const unsigned char* __restrict__ islm,
    const float* __restrict__ thr_p, const float* __restrict__ cxyz,
    const int* __restrict__ ktgt, int* __restrict__ keep,
    float4* __restrict__ klist, int* __restrict__ kidx,
    int* __restrict__ counters, float* __restrict__ out, int L) {
  int i = blockIdx.x * 256 + threadIdx.x;
  float thr = thr_p[0];
  float term = 0.f;
  if (i < L) {
    float p = pred[i];
    bool kp = (p > thr) || islm[i];
    keep[i] = kp ? 1 : 0;
    if (kp) {
      int pos = atomicAdd(&counters[0], 1);   // order irrelevant (no ties)
      float x = cxyz[3*i], y = cxyz[3*i+1], z = cxyz[3*i+2];
      klist[pos] = make_float4(x, y, z, fmaf(x, x, fmaf(y, y, z * z)));
      kidx[pos] = i;
    }
    float t = (float)ktgt[i];
    term = fmaxf(p, 0.f) - p * t + log1pf(expf(-fabsf(p)));
  }
  for (int o = 32; o > 0; o >>= 1) term += __shfl_down(term, o);
  if ((threadIdx.x & 63) == 0) atomicAdd(&out[0], term);
}

// ---- Kernel 4: dual-role scan (bwd y<YB, fwd y>=YB), LDS-tiled, no sync ----
__global__ __launch_bounds__(SCAN_T) void k_scan2(
    const float* __restrict__ txyz, const float4* __restrict__ klist,
    const int* __restrict__ kidx, const float4* __restrict__ ttile,
    const int* __restrict__ counters, ull* __restrict__ tmin,
    ull* __restrict__ fmin, int L, int N, int YB) {
  __shared__ float4 tile[SCAN_T];
  int tid = threadIdx.x, x = blockIdx.x, y = blockIdx.y;
  int kc = counters[0];

  if (y < YB) {
    // ---- backward: targets x*256.. vs kept-candidate chunk y (512) --------
    int c0 = y * 512;
    if (x * 256 >= N || c0 >= kc) return;   // uniform early-exit
    int c1 = min(c0 + 512, kc);
    int t = x * 256 + tid;
    bool act = t < N;
    float tx = 0.f, ty = 0.f, tz = 0.f;
    if (act) { tx = txyz[3*t]; ty = txyz[3*t+1]; tz = txyz[3*t+2]; }
    float ntx = -2.f * tx, nty = -2.f * ty, ntz = -2.f * tz;
    float best = 3e38f; int bpos = -1;
    for (int tb = c0; tb < c1; tb += SCAN_T) {
      int cnt = min(SCAN_T, c1 - tb);
      if (tid < cnt) tile[tid] = klist[tb + tid];
      __syncthreads();
      #pragma unroll 8
      for (int c = 0; c < cnt; ++c) {
        float4 cd = tile[c];
        // monotone surrogate |c|^2 - 2 t.c (argmin-equiv to |t-c|^2)
        float d = fmaf(ntx, cd.x, cd.w);
        d = fmaf(nty, cd.y, d);
        d = fmaf(ntz, cd.z, d);
        if (d < best) { best = d; bpos = tb + c; }
      }
      __syncthreads();
    }
    if (act && bpos >= 0) {
      float4 cd = klist[bpos];
      float dx = tx - cd.x, dy = ty - cd.y, dz = tz - cd.z;
      float dtrue = fmaf(dx, dx, fmaf(dy, dy, dz * dz));  // exact (R1-proven)
      ull pack = ((ull)__float_as_uint(dtrue) << 32) | (unsigned int)kidx[bpos];
      atomicMin(&tmin[t], pack);
    }
  } else {
    // ---- forward: ALL kept candidates x*256.. vs target chunk (512) -------
    int t0 = (y - YB) * 512;
    if (x * 256 >= kc) return;              // uniform early-exit
    int t1 = min(t0 + 512, N);
    int e = x * 256 + tid;
    bool act = e < kc;
    float cx = 0.f, cy = 0.f, cz = 0.f, c2 = 0.f;
    int l = 0;
    if (act) {
      float4 cd = klist[e];
      cx = cd.x; cy = cd.y; cz = cd.z; c2 = cd.w;
      l = kidx[e];
    }
    float ncx = -2.f * cx, ncy = -2.f * cy, ncz = -2.f * cz;
    float best = 3e38f; int bidx = 0;
    for (int tb = t0; tb < t1; tb += SCAN_T) {
      int cnt = min(SCAN_T, t1 - tb);
      if (tid < cnt) tile[tid] = ttile[tb + tid];
      __syncthreads();
      #pragma unroll 8
      for (int c = 0; c < cnt; ++c) {
        float4 td = tile[c];
        float d = fmaf(ncx, td.x, td.w);
        d = fmaf(ncy, td.y, d);
        d = fmaf(ncz, td.z, d);
        if (d < best) { best = d; bidx = tb + c; }
      }
      __syncthreads();
    }
    if (act) {
      float dkey = fmaxf(best + c2, 0.f);   // consistent merge key (R3-proven)
      ull pack = ((ull)__float_as_uint(dkey) << 32) | (unsigned int)bidx;
      atomicMin(&fmin[l], pack);
    }
  }
}

// ---- Kernel 5: scatter weighted colors into num/den ------------------------
__global__ __launch_bounds__(256) void k_scatter(
    const float* __restrict__ trgb, const ull* __restrict__ tmin,
    float4* __restrict__ numden, int* __restrict__ zerohit,
    float4* __restrict__ zcolor, int N) {
  int t = blockIdx.x * 256 + threadIdx.x;
  if (t >= N) return;
  ull pack = tmin[t];
  float d = __uint_as_float((unsigned int)(pack >> 32));
  int idx = (int)(pack & 0xFFFFFFFFull);
  float r = trgb[3*t], g = trgb[3*t+1], b = trgb[3*t+2];
  if (d == 0.0f) {
    zerohit[idx] = 1;
    zcolor[idx] = make_float4(r, g, b, 0.f);
  } else {
    float w = 1.0f / sqrtf(fmaxf(d, 1e-30f));
    atomicAdd(&numden[idx].x, r * w);
    atomicAdd(&numden[idx].y, g * w);
    atomicAdd(&numden[idx].z, b * w);
    atomicAdd(&numden[idx].w, w);
  }
}

// ---- Kernel 6: final recolor select + L1 reduce ----------------------------
__global__ __launch_bounds__(256) void k_loss(
    const float* __restrict__ crgb, const float* __restrict__ trgb,
    const int* __restrict__ keep, const float4* __restrict__ numden,
    const int* __restrict__ zerohit, const float4* __restrict__ zcolor,
    const ull* __restrict__ fmin, float* __restrict__ out, int L) {
  int l = blockIdx.x * 256 + threadIdx.x;
  float loss = 0.f;
  if (l < L && keep[l]) {
    float rr, rg, rb;
    if (zerohit[l]) {
      float4 z = zcolor[l]; rr = z.x; rg = z.y; rb = z.z;
    } else {
      float4 nd = numden[l];
      if (nd.w != 0.f) { rr = nd.x / nd.w; rg = nd.y / nd.w; rb = nd.z / nd.w; }
      else {
        int ti = (int)(fmin[l] & 0xFFFFFFFFull);
        rr = trgb[3*ti]; rg = trgb[3*ti+1]; rb = trgb[3*ti+2];
      }
    }
    float sr = crgb[3*l]*255.f, sg = crgb[3*l+1]*255.f, sb = crgb[3*l+2]*255.f;
    loss = fabsf(sr - rr) + fabsf(sg - rg) + fabsf(sb - rb);
  }
  for (int o = 32; o > 0; o >>= 1) loss += __shfl_down(loss, o);
  if ((threadIdx.x & 63) == 0) atomicAdd(&out[1], loss);
}

extern "C" void kernel_launch(void* const* d_in, const int* in_sizes, int n_in,
                              void* d_out, int out_size, void* d_ws, size_t ws_size,
                              hipStream_t stream) {
  const float* pred = (const float*)d_in[0];
  const float* cxyz = (const float*)d_in[1];
  const float* crgb = (const float*)d_in[2];
  const float* txyz = (const float*)d_in[3];
  const float* trgb = (const float*)d_in[4];
  const int*   ktgt = (const int*)d_in[5];
  const int*   pnum = (const int*)d_in[6];
  int L = in_sizes[0];
  int N = in_sizes[3] / 3;

  // workspace layout: 16B arrays first, then 8B, 4B, bytes
  char* ws = (char*)d_ws;
  size_t off = 0;
  float4* klist  = (float4*)(ws + off);   off += (size_t)L * 16;
  float4* ttile  = (float4*)(ws + off);   off += (size_t)((N + 3) & ~3) * 16;
  float4* numden = (float4*)(ws + off);   off += (size_t)L * 16;
  float4* zcolor = (float4*)(ws + off);   off += (size_t)L * 16;
  unsigned int* key = (unsigned int*)(ws + off); off += (size_t)L * 4;  // uint4-aligned
  ull* tmin      = (ull*)(ws + off);      off += (size_t)((N + 1) & ~1) * 8;
  ull* fmin      = (ull*)(ws + off);      off += (size_t)L * 8;
  int* keep      = (int*)(ws + off);      off += (size_t)L * 4;
  int* kidx      = (int*)(ws + off);      off += (size_t)L * 4;
  int* zerohit   = (int*)(ws + off);      off += (size_t)L * 4;
  float* thr_slot = (float*)(ws + off);   off += 16;
  int* counters  = (int*)(ws + off);      off += 256;   // [0]=kcount
  unsigned char* islm = (unsigned char*)(ws + off); off += ((size_t)L + 15) & ~15ull;
  float* out = (float*)d_out;

  int nbL = (L + 255) / 256;   // 64
  int nbN = (N + 255) / 256;   // 40
  int YB = (L + 511) / 512;    // 32 kept-chunks (early-exit trims to kc)
  int YF = (N + 511) / 512;    // 20 target-chunks
  int mx = max(L, N);

  k_prep<<<(mx + 255) / 256, 256, 0, stream>>>(
      pred, txyz, ttile, numden, zerohit, tmin, fmin, key, islm, counters, out, L, N);

  k_sel<<<1, 256, 0, stream>>>(key, pnum, thr_slot, L);

  k_keepc<<<nbL, 256, 0, stream>>>(
      pred, islm, thr_slot, cxyz, ktgt, keep, klist, kidx, counters, out, L);

  dim3 gs(nbL, YB + YF);   // x covers max(targets, kept); roles early-exit
  k_scan2<<<gs, SCAN_T, 0, stream>>>(
      txyz, klist, kidx, ttile, counters, tmin, fmin, L, N, YB);

  k_scatter<<<nbN, 256, 0, stream>>>(trgb, tmin, numden, zerohit, zcolor, N);

  k_loss<<<nbL, 256, 0, stream>>>(
      crgb, trgb, keep, numden, zerohit, zcolor, fmin, out, L);
}